// Round 6
// baseline (1469.837 us; speedup 1.0000x reference)
//
#include <hip/hip_runtime.h>
#include <math.h>

// Problem constants
#define B_ 32
#define T_ 2048
#define D_ 256
#define H_ 512
#define O_ 256
#define S_CH 8               // chunk length
#define C_CH 256             // number of chunks = T/S: 1 block per CU

typedef short bf16x8 __attribute__((ext_vector_type(8)));  // 8 bf16 (4 VGPRs) MFMA frag
typedef float f32x4  __attribute__((ext_vector_type(4)));

#define NTL(p)     __builtin_nontemporal_load(p)

__device__ __forceinline__ unsigned short f2bf_rne(float x) {
    unsigned int u = __builtin_bit_cast(unsigned int, x);
    unsigned int r = (u + 0x7fffu + ((u >> 16) & 1u)) >> 16;
    return (unsigned short)r;
}
__device__ __forceinline__ float bf2f(unsigned short h) {
    unsigned int u = ((unsigned int)h) << 16;
    return __builtin_bit_cast(float, u);
}

#define MFMA16(a, b, c) __builtin_amdgcn_mfma_f32_16x16x32_bf16((a), (b), (c), 0, 0, 0)

// Build split-bf16 A-fragments (hi+lo) from 8 consecutive fp32 values.
__device__ __forceinline__ void split_frag(const float* p, bf16x8& hi, bf16x8& lo) {
    f32x4 a = *(const f32x4*)p;
    f32x4 b = *(const f32x4*)(p + 4);
#pragma unroll
    for (int i = 0; i < 4; i++) {
        unsigned short h = f2bf_rne(a[i]);
        hi[i] = (short)h; lo[i] = (short)f2bf_rne(a[i] - bf2f(h));
        unsigned short h2 = f2bf_rne(b[i]);
        hi[4 + i] = (short)h2; lo[4 + i] = (short)f2bf_rne(b[i] - bf2f(h2));
    }
}
// Same, but non-temporal loads (pure read-once streams: x, zq).
__device__ __forceinline__ void split_frag_nt(const float* p, bf16x8& hi, bf16x8& lo) {
    f32x4 a = NTL((const f32x4*)p);
    f32x4 b = NTL((const f32x4*)(p + 4));
#pragma unroll
    for (int i = 0; i < 4; i++) {
        unsigned short h = f2bf_rne(a[i]);
        hi[i] = (short)h; lo[i] = (short)f2bf_rne(a[i] - bf2f(h));
        unsigned short h2 = f2bf_rne(b[i]);
        hi[4 + i] = (short)h2; lo[4 + i] = (short)f2bf_rne(b[i] - bf2f(h2));
    }
}

// Fragment-major packed offset for a B-matrix element (n, k), KB = K/32.
__device__ __forceinline__ size_t wpack_off(int n, int k, int KB) {
    int n16 = n >> 4, l15 = n & 15;
    int kb = k >> 5, lhi = (k >> 3) & 3, j = k & 7;
    return (((size_t)(n16 * KB + kb) * 4 + lhi) * 16 + l15) * 8 + j;
}

// Same layout for the LDS-resident h state (m over 32 batches, n over 512).
__device__ __forceinline__ int hfrag_off(int m, int n) {
    int m16 = m >> 4, l15m = m & 15;
    int kb = n >> 5, lhi = (n >> 3) & 3, j = n & 7;
    return (((m16 * 16 + kb) * 4 + lhi) * 16 + l15m) * 8 + j;
}

// ---------------------------------------------------------------------------
// Pack fp32 matrix into frag-major bf16 hi/lo (optional 2nd dest).
// kshift: 9 (K=512) or 8 (K=256).
// ---------------------------------------------------------------------------
__global__ void k_pack(const float* __restrict__ in, unsigned short* __restrict__ hi,
                       unsigned short* __restrict__ lo, unsigned short* __restrict__ hi2,
                       unsigned short* __restrict__ lo2, int total, int kshift) {
    int i = blockIdx.x * 256 + threadIdx.x;
    if (i < total) {
        int n = i >> kshift;
        int k = i & ((1 << kshift) - 1);
        float v = in[i];
        unsigned short h = f2bf_rne(v);
        unsigned short l = f2bf_rne(v - bf2f(h));
        size_t o = wpack_off(n, k, 1 << (kshift - 5));
        hi[o] = h;
        lo[o] = l;
        if (hi2) { hi2[o] = h; lo2[o] = l; }
    }
}

// ---------------------------------------------------------------------------
// fp32 matmul body: Out = A * Bm (512x512 row-major), blockIdx.x/y tile.
// Fused epilogue: optional packed (frag-major bf16 hi/lo) dests d1, d2.
// ---------------------------------------------------------------------------
__device__ __forceinline__ void mul_body(const float* __restrict__ A,
                                         const float* __restrict__ Bm,
                                         float* __restrict__ Out,
                                         unsigned short* __restrict__ d1h,
                                         unsigned short* __restrict__ d1l,
                                         unsigned short* __restrict__ d2h,
                                         unsigned short* __restrict__ d2l,
                                         float (*As)[33], float (*Bs)[33]) {
    int tx = threadIdx.x & 15, ty = threadIdx.x >> 4;
    int j0 = blockIdx.x * 32, i0 = blockIdx.y * 32;
    float a00 = 0.f, a01 = 0.f, a10 = 0.f, a11 = 0.f;
    int r  = threadIdx.x >> 3;
    int c4 = (threadIdx.x & 7) * 4;
    for (int kb = 0; kb < H_ / 32; kb++) {
        f32x4 va = *(const f32x4*)(A + (size_t)(i0 + r) * H_ + kb * 32 + c4);
        f32x4 vb = *(const f32x4*)(Bm + (size_t)(kb * 32 + r) * H_ + j0 + c4);
        __syncthreads();
        As[r][c4 + 0] = va[0]; As[r][c4 + 1] = va[1]; As[r][c4 + 2] = va[2]; As[r][c4 + 3] = va[3];
        Bs[r][c4 + 0] = vb[0]; Bs[r][c4 + 1] = vb[1]; Bs[r][c4 + 2] = vb[2]; Bs[r][c4 + 3] = vb[3];
        __syncthreads();
#pragma unroll
        for (int k = 0; k < 32; k++) {
            float b0 = Bs[k][tx * 2], b1 = Bs[k][tx * 2 + 1];
            float a0 = As[ty * 2][k], a1 = As[ty * 2 + 1][k];
            a00 += a0 * b0; a01 += a0 * b1; a10 += a1 * b0; a11 += a1 * b1;
        }
    }
    float vals[4] = {a00, a01, a10, a11};
#pragma unroll
    for (int q = 0; q < 4; q++) {
        int n = i0 + ty * 2 + (q >> 1);
        int k = j0 + tx * 2 + (q & 1);
        Out[(size_t)n * H_ + k] = vals[q];
        unsigned short h = f2bf_rne(vals[q]);
        unsigned short l = f2bf_rne(vals[q] - bf2f(h));
        size_t o = wpack_off(n, k, 16);
        if (d1h) { d1h[o] = h; d1l[o] = l; }
        if (d2h) { d2h[o] = h; d2l[o] = l; }
    }
}

__global__ __launch_bounds__(256) void k_mul(const float* __restrict__ A,
                                             const float* __restrict__ Bm,
                                             float* __restrict__ Out,
                                             unsigned short* __restrict__ d1h,
                                             unsigned short* __restrict__ d1l,
                                             unsigned short* __restrict__ d2h,
                                             unsigned short* __restrict__ d2l) {
    __shared__ float As[32][33];
    __shared__ float Bs[32][33];
    mul_body(A, Bm, Out, d1h, d1l, d2h, d2l, As, Bs);
}

// Two independent products per launch: z=0: W^3 = W*W^2 -> M1 (pack Pp2);
// z=1: W^4 = W^2*W^2 -> M2 (pack Pp3). M base = ws.
__global__ __launch_bounds__(256) void k_mul_l2(const float* __restrict__ Whh,
                                                float* __restrict__ ws,
                                                unsigned short* __restrict__ Pp_hi,
                                                unsigned short* __restrict__ Pp_lo) {
    __shared__ float As[32][33];
    __shared__ float Bs[32][33];
    size_t HH = (size_t)H_ * H_;
    if (blockIdx.z == 0)
        mul_body(Whh, ws, ws + HH, Pp_hi + 2 * HH, Pp_lo + 2 * HH, nullptr, nullptr, As, Bs);
    else
        mul_body(ws, ws, ws + 2 * HH, Pp_hi + 3 * HH, Pp_lo + 3 * HH, nullptr, nullptr, As, Bs);
}

// Four independent products: z=0: W^5=W*W^4->M3(Pp4); z=1: W^6=W^2*W^4->M4(Pp5);
// z=2: W^7=W^3*W^4->M5(Pp6); z=3: W^8=W^4*W^4->M6(Pp7+Qp0).
__global__ __launch_bounds__(256) void k_mul_l3(const float* __restrict__ Whh,
                                                float* __restrict__ ws,
                                                unsigned short* __restrict__ Pp_hi,
                                                unsigned short* __restrict__ Pp_lo,
                                                unsigned short* __restrict__ Qp_hi,
                                                unsigned short* __restrict__ Qp_lo) {
    __shared__ float As[32][33];
    __shared__ float Bs[32][33];
    size_t HH = (size_t)H_ * H_;
    float* M0 = ws;           // W^2
    float* M1 = ws + HH;      // W^3
    float* M2 = ws + 2 * HH;  // W^4
    int z = blockIdx.z;
    if (z == 0)
        mul_body(Whh, M2, ws + 3 * HH, Pp_hi + 4 * HH, Pp_lo + 4 * HH, nullptr, nullptr, As, Bs);
    else if (z == 1)
        mul_body(M0, M2, ws + 4 * HH, Pp_hi + 5 * HH, Pp_lo + 5 * HH, nullptr, nullptr, As, Bs);
    else if (z == 2)
        mul_body(M1, M2, ws + 5 * HH, Pp_hi + 6 * HH, Pp_lo + 6 * HH, nullptr, nullptr, As, Bs);
    else
        mul_body(M2, M2, ws + 6 * HH, Pp_hi + 7 * HH, Pp_lo + 7 * HH, Qp_hi, Qp_lo, As, Bs);
}

// ---------------------------------------------------------------------------
// Seed the chunk-carry scan inputs: v[0]=h0, v[c]=l_end(c-1) from zb.
// ---------------------------------------------------------------------------
__global__ void k_seed(const float* __restrict__ h0, const float* __restrict__ zb,
                       float* __restrict__ Va) {
    int i = blockIdx.x * 256 + threadIdx.x;  // over C*B*H
    int c = i >> 14;             // B*H = 16384
    int bn = i & 16383;
    int b = bn >> 9, n = bn & 511;
    Va[i] = (c == 0) ? h0[bn] : zb[((size_t)b * T_ + (c * S_CH - 1)) * H_ + n];
}

// ---------------------------------------------------------------------------
// One Kogge-Stone scan level via split-bf16 MFMA:
// Vout[c] = Vin[c] + Vin[c-s] @ (W^(S*s))^T  (c >= s), else copy.
// grid C_CH, block 1024 (16 waves; wave w owns 32-col n-slice, nt 0..1).
// ---------------------------------------------------------------------------
__global__ __launch_bounds__(1024) void k_scan2(const float* __restrict__ Vin,
                                                const unsigned short* __restrict__ Qp_hi,
                                                const unsigned short* __restrict__ Qp_lo,
                                                float* __restrict__ Vout, int s) {
    __shared__ __attribute__((aligned(16))) unsigned short hA[16384];
    __shared__ __attribute__((aligned(16))) unsigned short lA[16384];
    int c = blockIdx.x;
    int w = threadIdx.x >> 6;
    int lane = threadIdx.x & 63;
    int l15 = lane & 15, lhi = lane >> 4;

    if (c < s) {  // pure copy
        size_t base = (size_t)c * B_ * H_;
        for (int i = threadIdx.x * 4; i < B_ * H_; i += 4096) {
            f32x4 v = *(const f32x4*)(Vin + base + i);
            *(f32x4*)(Vout + base + i) = v;
        }
        return;
    }

    // stage Vin[c-s] as split-bf16 frag-major in LDS
    size_t src = (size_t)(c - s) * B_ * H_;
    for (int i = threadIdx.x; i < 16384; i += 1024) {
        float v = Vin[src + i];               // i = m*512 + n, row-major
        int m = i >> 9, n = i & 511;
        unsigned short hi = f2bf_rne(v);
        int o = hfrag_off(m, n);
        hA[o] = hi;
        lA[o] = f2bf_rne(v - bf2f(hi));
    }
    __syncthreads();

    // issue the additive Vin[c] loads early (overlap with MFMA)
    size_t dst = (size_t)c * B_ * H_;
    float ad[2][2][4];
#pragma unroll
    for (int mt = 0; mt < 2; mt++)
#pragma unroll
        for (int nt = 0; nt < 2; nt++) {
            int n = w * 32 + nt * 16 + l15;
#pragma unroll
            for (int r = 0; r < 4; r++) {
                int m = mt * 16 + lhi * 4 + r;
                ad[mt][nt][r] = Vin[dst + (size_t)m * H_ + n];
            }
        }

    f32x4 acc[2][2];
#pragma unroll
    for (int mt = 0; mt < 2; mt++)
#pragma unroll
        for (int nt = 0; nt < 2; nt++) acc[mt][nt] = (f32x4){0.f, 0.f, 0.f, 0.f};

    for (int kb = 0; kb < 16; kb++) {
        bf16x8 ah0 = *(const bf16x8*)&hA[(kb << 9) + lane * 8];
        bf16x8 ah1 = *(const bf16x8*)&hA[((16 + kb) << 9) + lane * 8];
        bf16x8 al0 = *(const bf16x8*)&lA[(kb << 9) + lane * 8];
        bf16x8 al1 = *(const bf16x8*)&lA[((16 + kb) << 9) + lane * 8];
#pragma unroll
        for (int nt = 0; nt < 2; nt++) {
            size_t wb = (((size_t)(w * 2 + nt) * 16 + kb) << 9) + lane * 8;
            bf16x8 bh = *(const bf16x8*)(Qp_hi + wb);
            bf16x8 bl = *(const bf16x8*)(Qp_lo + wb);
            acc[0][nt] = MFMA16(ah0, bh, acc[0][nt]);
            acc[0][nt] = MFMA16(al0, bh, acc[0][nt]);
            acc[0][nt] = MFMA16(ah0, bl, acc[0][nt]);
            acc[1][nt] = MFMA16(ah1, bh, acc[1][nt]);
            acc[1][nt] = MFMA16(al1, bh, acc[1][nt]);
            acc[1][nt] = MFMA16(ah1, bl, acc[1][nt]);
        }
    }
#pragma unroll
    for (int mt = 0; mt < 2; mt++)
#pragma unroll
        for (int nt = 0; nt < 2; nt++) {
            int n = w * 32 + nt * 16 + l15;
#pragma unroll
            for (int r = 0; r < 4; r++) {
                int m = mt * 16 + lhi * 4 + r;
                Vout[dst + (size_t)m * H_ + n] = acc[mt][nt][r] + ad[mt][nt][r];
            }
        }
}

// ---------------------------------------------------------------------------
// K0: zb[b][t][h] = x[b][t][:] @ W_ih^T + (b_ih + b_hh), fp32, into the z
// region of d_out. x split hi/lo on the fly; W_ih pre-split+packed; 3 MFMAs.
// grid (T/64, B), block 512 (8 waves; wave w owns n-slice 64w..64w+63)
// ---------------------------------------------------------------------------
__global__ __launch_bounds__(512) void k_xw(const float* __restrict__ x,
                                            const unsigned short* __restrict__ Wp_hi,
                                            const unsigned short* __restrict__ Wp_lo,
                                            const float* __restrict__ bih,
                                            const float* __restrict__ bhh,
                                            float* __restrict__ zb) {
    int b  = blockIdx.y;
    int t0 = blockIdx.x * 64;
    int w    = threadIdx.x >> 6;
    int lane = threadIdx.x & 63;
    int l15 = lane & 15, lhi = lane >> 4;
    int nb = w * 64;

    f32x4 acc[4][4];  // [mt][nt]
    for (int mt = 0; mt < 4; mt++)
        for (int nt = 0; nt < 4; nt++)
            acc[mt][nt] = (f32x4){0.f, 0.f, 0.f, 0.f};

    const float* xb = x + (size_t)b * T_ * D_;
    for (int kb = 0; kb < D_ / 32; kb++) {
        int kofs = kb * 32 + lhi * 8;
        bf16x8 ah[4], al[4];
#pragma unroll
        for (int mt = 0; mt < 4; mt++) {
            int t = t0 + mt * 16 + l15;
            split_frag_nt(xb + (size_t)t * D_ + kofs, ah[mt], al[mt]);
        }
#pragma unroll
        for (int nt = 0; nt < 4; nt++) {
            size_t wb = (((size_t)(w * 4 + nt) * 8 + kb) << 9) + lane * 8;  // KB=8
            bf16x8 bh = *(const bf16x8*)(Wp_hi + wb);
            bf16x8 bl = *(const bf16x8*)(Wp_lo + wb);
#pragma unroll
            for (int mt = 0; mt < 4; mt++) {
                acc[mt][nt] = MFMA16(ah[mt], bh, acc[mt][nt]);
                acc[mt][nt] = MFMA16(al[mt], bh, acc[mt][nt]);
                acc[mt][nt] = MFMA16(ah[mt], bl, acc[mt][nt]);
            }
        }
    }
#pragma unroll
    for (int nt = 0; nt < 4; nt++) {
        int n = nb + nt * 16 + l15;
        float bias = bih[n] + bhh[n];
#pragma unroll
        for (int mt = 0; mt < 4; mt++) {
#pragma unroll
            for (int r = 0; r < 4; r++) {
                int t = t0 + mt * 16 + lhi * 4 + r;
                zb[((size_t)b * T_ + t) * H_ + n] = acc[mt][nt][r] + bias;
            }
        }
    }
}

// ---------------------------------------------------------------------------
// Phase 1: per-chunk local recurrence l_t = xw_t + l_{t-1} @ W_hh^T (from 0),
// in place over zb (fp32, [b][t][h]). State fp32 via split-bf16 hi/lo LDS.
// Whh fragments (this wave's 2 n-slices x 16 kb, hi+lo = 256 VGPR) preloaded
// into registers ONCE — removes the 1 MB/step L2 weight re-stream from the
// barrier-serialized critical path. grid C_CH, block 1024 (16 waves).
// ---------------------------------------------------------------------------
__global__ __launch_bounds__(1024) void k_phase1(const unsigned short* __restrict__ Wp_hi,
                                                 const unsigned short* __restrict__ Wp_lo,
                                                 float* __restrict__ zb) {
    __shared__ __attribute__((aligned(16))) unsigned short hA[16384];
    __shared__ __attribute__((aligned(16))) unsigned short lA[16384];
    int c = blockIdx.x;
    int w = threadIdx.x >> 6;
    int lane = threadIdx.x & 63;
    int l15 = lane & 15, lhi = lane >> 4;

    // one-time weight preload into VGPRs (compile-time indexed -> registers)
    bf16x8 wh[2][16], wl[2][16];
#pragma unroll
    for (int nt = 0; nt < 2; nt++)
#pragma unroll
        for (int kb = 0; kb < 16; kb++) {
            size_t wb = (((size_t)(w * 2 + nt) * 16 + kb) << 9) + lane * 8;
            wh[nt][kb] = *(const bf16x8*)(Wp_hi + wb);
            wl[nt][kb] = *(const bf16x8*)(Wp_lo + wb);
        }

    for (int j = 0; j < S_CH; j++) {
        int t = c * S_CH + j;
        // issue this step's xw loads early; they resolve under the MFMA loop
        float xw[2][2][4];
#pragma unroll
        for (int mt = 0; mt < 2; mt++)
#pragma unroll
            for (int nt = 0; nt < 2; nt++) {
                int n = w * 32 + nt * 16 + l15;
#pragma unroll
                for (int r = 0; r < 4; r++) {
                    int b = mt * 16 + lhi * 4 + r;
                    xw[mt][nt][r] = zb[((size_t)b * T_ + t) * H_ + n];
                }
            }
        f32x4 acc[2][2];
#pragma unroll
        for (int mt = 0; mt < 2; mt++)
#pragma unroll
            for (int nt = 0; nt < 2; nt++) acc[mt][nt] = (f32x4){0.f, 0.f, 0.f, 0.f};
        if (j > 0) {
#pragma unroll
            for (int kb = 0; kb < 16; kb++) {
                bf16x8 ah0 = *(const bf16x8*)&hA[(kb << 9) + lane * 8];
                bf16x8 ah1 = *(const bf16x8*)&hA[((16 + kb) << 9) + lane * 8];
                bf16x8 al0 = *(const bf16x8*)&lA[(kb << 9) + lane * 8];
                bf16x8 al1 = *(const bf16x8*)&lA[((16 + kb) << 9) + lane * 8];
#pragma unroll
                for (int nt = 0; nt < 2; nt++) {
                    acc[0][nt] = MFMA16(ah0, wh[nt][kb], acc[0][nt]);
                    acc[0][nt] = MFMA16(al0, wh[nt][kb], acc[0][nt]);
                    acc[0][nt] = MFMA16(ah0, wl[nt][kb], acc[0][nt]);
                    acc[1][nt] = MFMA16(ah1, wh[nt][kb], acc[1][nt]);
                    acc[1][nt] = MFMA16(al1, wh[nt][kb], acc[1][nt]);
                    acc[1][nt] = MFMA16(ah1, wl[nt][kb], acc[1][nt]);
                }
            }
        }
        __syncthreads();  // all waves done reading previous h before overwrite
#pragma unroll
        for (int mt = 0; mt < 2; mt++) {
#pragma unroll
            for (int nt = 0; nt < 2; nt++) {
                int n = w * 32 + nt * 16 + l15;
#pragma unroll
                for (int r = 0; r < 4; r++) {
                    int b = mt * 16 + lhi * 4 + r;
                    float v = acc[mt][nt][r] + xw[mt][nt][r];
                    zb[((size_t)b * T_ + t) * H_ + n] = v;  // l_t (fp32)
                    unsigned short hi = f2bf_rne(v);
                    int o = hfrag_off(b, n);
                    hA[o] = hi;
                    lA[o] = f2bf_rne(v - bf2f(hi));
                }
            }
        }
        __syncthreads();
    }
}

// ---------------------------------------------------------------------------
// Carry broadcast as ONE GEMM (replaces the serial phase 3):
//   zb[b][c*8+j][n] += Hin[c][b][:] @ (W^(j+1))^T
// A = Hin (8192 x 512 fp32), B = Pp (stacked W^1..W^8, 4096 x 512 packed).
// M=8192, N=4096, K=512. BM=128, BN=256, block 512 (8 waves as 2M x 4N).
// XCD swizzle: each XCD owns 8 contiguous M-tiles (2 MB of Hin, L2-resident)
// x all 16 N-panels — Hin HBM read once (16 MB) instead of per-panel (256 MB).
// ---------------------------------------------------------------------------
__global__ __launch_bounds__(512) void k_carry(const float* __restrict__ Hin,
                                               const unsigned short* __restrict__ Pp_hi,
                                               const unsigned short* __restrict__ Pp_lo,
                                               float* __restrict__ zb) {
    int bid = blockIdx.x;
    int xcd = bid & 7;
    int idx = bid >> 3;                       // 0..127
    int mtile  = xcd * 8 + (idx & 7);         // 0..63 (8 contiguous per XCD)
    int npanel = idx >> 3;                    // 0..15
    int w = threadIdx.x >> 6, lane = threadIdx.x & 63;
    int l15 = lane & 15, lhi = lane >> 4;
    int wm = w >> 2, wn = w & 3;
    int m0 = mtile * 128 + wm * 64;
    int n16base = npanel * 16 + wn * 4;       // global 16-col fragment index

    f32x4 acc[4][4];
#pragma unroll
    for (int mt = 0; mt < 4; mt++)
#pragma unroll
        for (int nt = 0; nt < 4; nt++) acc[mt][nt] = (f32x4){0.f, 0.f, 0.f, 0.f};

    for (int kb = 0; kb < 16; kb++) {
        int kofs = kb * 32 + lhi * 8;
        bf16x8 ah[4], al[4];
#pragma unroll
        for (int mt = 0; mt < 4; mt++)
            split_frag(Hin + (size_t)(m0 + mt * 16 + l15) * H_ + kofs, ah[mt], al[mt]);
#pragma unroll
        for (int nt = 0; nt < 4; nt++) {
            size_t wb = (((size_t)(n16base + nt) * 16 + kb) << 9) + lane * 8;
            bf16x8 bh = *(const bf16x8*)(Pp_hi + wb);
            bf16x8 bl = *(const bf16x8*)(Pp_lo + wb);
#pragma unroll
            for (int mt = 0; mt < 4; mt++) {
                acc[mt][nt] = MFMA16(ah[mt], bh, acc[mt][nt]);
                acc[mt][nt] = MFMA16(al[mt], bh, acc[mt][nt]);
                acc[mt][nt] = MFMA16(ah[mt], bl, acc[mt][nt]);
            }
        }
    }
    // epilogue: z_t = l_t + acc, scattered into zb[b][t][n]
#pragma unroll
    for (int nt = 0; nt < 4; nt++) {
        int col = (n16base + nt) * 16 + l15;  // 0..4095
        int j = col >> 9, n = col & 511;
#pragma unroll
        for (int mt = 0; mt < 4; mt++) {
#pragma unroll
            for (int r = 0; r < 4; r++) {
                int m = m0 + mt * 16 + lhi * 4 + r;   // (c,b) row
                int c = m >> 5, b = m & 31;
                size_t zi = ((size_t)b * T_ + (c * S_CH + j)) * H_ + n;
                zb[zi] += acc[mt][nt][r];
            }
        }
    }
}

// ---------------------------------------------------------------------------
// K5: logits = z @ W_lin^T + b_lin, fused softmax over O=256, fp32 out.
// grid (B*T/64), block 256 (4 waves; wave w owns rows 16w..16w+15, all cols).
// ---------------------------------------------------------------------------
__global__ __launch_bounds__(256) void k_logits(const float* __restrict__ zq,
                                                const unsigned short* __restrict__ Wp_hi,
                                                const float* __restrict__ blin,
                                                float* __restrict__ out) {
    size_t row0 = (size_t)blockIdx.x * 64;
    int w = threadIdx.x >> 6, lane = threadIdx.x & 63;
    int l15 = lane & 15, lhi = lane >> 4;

    f32x4 acc[16];
#pragma unroll
    for (int nt = 0; nt < 16; nt++) acc[nt] = (f32x4){0.f, 0.f, 0.f, 0.f};

    const float* arow = zq + (row0 + (size_t)w * 16 + l15) * H_;
    for (int kb = 0; kb < 16; kb++) {
        int kofs = kb * 32 + lhi * 8;
        bf16x8 ah, al;
        split_frag_nt(arow + kofs, ah, al);
#pragma unroll
        for (int nt = 0; nt < 16; nt++) {
            size_t wb = (((size_t)nt * 16 + kb) << 9) + lane * 8;  // n16 = nt, KB=16
            bf16x8 bh = *(const bf16x8*)(Wp_hi + wb);
            acc[nt] = MFMA16(ah, bh, acc[nt]);
            acc[nt] = MFMA16(al, bh, acc[nt]);
        }
    }
#pragma unroll
    for (int nt = 0; nt < 16; nt++) {
        float bb = blin[nt * 16 + l15];
#pragma unroll
        for (int r = 0; r < 4; r++) acc[nt][r] += bb;
    }
    float rmax[4], rinv[4];
#pragma unroll
    for (int r = 0; r < 4; r++) {
        float mx = -INFINITY;
#pragma unroll
        for (int nt = 0; nt < 16; nt++) mx = fmaxf(mx, acc[nt][r]);
        for (int s = 1; s < 16; s <<= 1) mx = fmaxf(mx, __shfl_xor(mx, s));
        float sum = 0.f;
#pragma unroll
        for (int nt = 0; nt < 16; nt++) sum += __expf(acc[nt][r] - mx);
        for (int s = 1; s < 16; s <<= 1) sum += __shfl_xor(sum, s);
        rmax[r] = mx;
        rinv[r] = 1.f / sum;
    }
#pragma unroll
    for (int nt = 0; nt < 16; nt++) {
#pragma unroll
        for (int r = 0; r < 4; r++) {
            float e = __expf(acc[nt][r] - rmax[r]) * rinv[r];
            size_t row = row0 + (size_t)w * 16 + lhi * 4 + r;
            out[row * O_ + nt * 16 + l15] = e;
        }
    }
}

// ---------------------------------------------------------------------------
extern "C" void kernel_launch(void* const* d_in, const int* in_sizes, int n_in,
                              void* d_out, int out_size, void* d_ws, size_t ws_size,
                              hipStream_t stream) {
    const float* x    = (const float*)d_in[0];
    const float* h0   = (const float*)d_in[1];
    const float* Wih  = (const float*)d_in[2];
    const float* Whh  = (const float*)d_in[3];
    const float* bih  = (const float*)d_in[4];
    const float* bhh  = (const float*)d_in[5];
    const float* Wlin = (const float*)d_in[6];
    const float* blin = (const float*)d_in[7];

    float* out  = (float*)d_out;
    float* zout = out + (size_t)B_ * T_ * O_;  // z region of d_out (fp32, in-place)

    // ws layout (~15 MB): M[0..13] fp32 power matrices | small packed weights.
    // Large packed power sets (Pp, Qp: 16 MB) + Va/Vb (32 MB) live in the
    // softmax-out region of d_out, dead until k_logits (the final launch).
    float* ws = (float*)d_ws;
    size_t HH = (size_t)H_ * H_;
    float* M13 = ws + (size_t)13 * HH;
    unsigned short* Wih_hi  = (unsigned short*)(ws + (size_t)14 * HH);
    unsigned short* Wih_lo  = Wih_hi + (size_t)H_ * D_;
    unsigned short* Wlin_hi = Wih_lo + (size_t)H_ * D_;
    unsigned short* Wlin_lo = Wlin_hi + (size_t)O_ * H_;

    float* Va = out;                            // [0,16MB)
    float* Vb = out + (size_t)C_CH * B_ * H_;   // [16,32MB)
    unsigned short* Pp_hi = (unsigned short*)((char*)d_out + (size_t)32 * 1024 * 1024);
    unsigned short* Pp_lo = Pp_hi + (size_t)8 * HH;   // [36,40MB)
    unsigned short* Qp_hi = Pp_lo + (size_t)8 * HH;   // [40,44MB)
    unsigned short* Qp_lo = Qp_hi + (size_t)8 * HH;   // [44,48MB) < 64MB ✓

    unsigned short* nul = nullptr;

    // Pack direct-use weights. Whh packed once into Pp slice 0 (phase1 reads
    // the same layout there — Whh_hi/lo eliminated).
    k_pack<<<dim3((H_ * H_) / 256), 256, 0, stream>>>(Whh, Pp_hi, Pp_lo, nul, nul, H_ * H_, 9);
    k_pack<<<dim3((H_ * D_) / 256), 256, 0, stream>>>(Wih, Wih_hi, Wih_lo, nul, nul, H_ * D_, 8);
    k_pack<<<dim3((O_ * H_) / 256), 256, 0, stream>>>(Wlin, Wlin_hi, Wlin_lo, nul, nul, O_ * H_, 9);

    // fp32 power chain with fused packing, merged independent products:
    // W^2 -> M0 (Pp1); {W^3,W^4} -> M1,M2 (Pp2,Pp3); {W^5..W^8} -> M3..M6
    // (Pp4..Pp7, Qp0); then 7 serial squarings W^16..W^1024 -> Qp1..Qp7.
    dim3 g16(16, 16);
#define QPH(s) (Qp_hi + (size_t)(s) * HH)
#define QPL(s) (Qp_lo + (size_t)(s) * HH)
    k_mul<<<g16, 256, 0, stream>>>(Whh, Whh, ws, Pp_hi + HH, Pp_lo + HH, nul, nul); // W^2
    k_mul_l2<<<dim3(16, 16, 2), 256, 0, stream>>>(Whh, ws, Pp_hi, Pp_lo);           // W^3,W^4
    k_mul_l3<<<dim3(16, 16, 4), 256, 0, stream>>>(Whh, ws, Pp_hi, Pp_lo, Qp_hi, Qp_lo); // W^5..W^8
    for (int i = 7; i < 14; i++)                      // W^16..W^1024 -> Qp 1..7
        k_mul<<<g16, 256, 0, stream>>>(ws + (size_t)(i - 1) * HH, ws + (size_t)(i - 1) * HH,
                                       ws + (size_t)i * HH, QPH(i - 6), QPL(i - 6), nul, nul);
#undef QPH
#undef QPL
    (void)M13;

    // xw into z region
    k_xw<<<dim3(T_ / 64, B_), 512, 0, stream>>>(x, Wih_hi, Wih_lo, bih, bhh, zout);

    // local chunk scans (256 chunks of 8 steps), 16 waves/block, weights in VGPR
    k_phase1<<<dim3(C_CH), 1024, 0, stream>>>(Pp_hi, Pp_lo, zout);

    // chunk-carry Kogge-Stone scan (split-bf16 MFMA): level l shift 2^l
    k_seed<<<dim3((C_CH * B_ * H_) / 256), 256, 0, stream>>>(h0, zout, Va);
    {
        float* vin = Va;
        float* vout = Vb;
        int s = 1;
        for (int l = 0; l < 8; l++) {
            k_scan2<<<dim3(C_CH), 1024, 0, stream>>>(
                vin, Qp_hi + (size_t)l * HH, Qp_lo + (size_t)l * HH, vout, s);
            float* tmp = vin; vin = vout; vout = tmp;
            s <<= 1;
        }
        // 8 swaps -> final result back in Va
    }

    // carry broadcast as one big GEMM + in-place add into zb
    k_carry<<<dim3(1024), 512, 0, stream>>>(Va, Pp_hi, Pp_lo, zout);

    // logits + softmax
    k_logits<<<dim3((B_ * T_) / 64), 256, 0, stream>>>(zout, Wlin_hi, blin, out);
}

// Round 7
// 1328.059 us; speedup vs baseline: 1.1068x; 1.1068x over previous
//
#include <hip/hip_runtime.h>
#include <math.h>

// Problem constants
#define B_ 32
#define T_ 2048
#define D_ 256
#define H_ 512
#define O_ 256
#define S_CH 8               // chunk length
#define C_CH 256             // number of chunks = T/S: 1 block per CU

typedef short bf16x8 __attribute__((ext_vector_type(8)));  // 8 bf16 (4 VGPRs) MFMA frag
typedef float f32x4  __attribute__((ext_vector_type(4)));

#define NTL(p)     __builtin_nontemporal_load(p)

__device__ __forceinline__ unsigned short f2bf_rne(float x) {
    unsigned int u = __builtin_bit_cast(unsigned int, x);
    unsigned int r = (u + 0x7fffu + ((u >> 16) & 1u)) >> 16;
    return (unsigned short)r;
}
__device__ __forceinline__ float bf2f(unsigned short h) {
    unsigned int u = ((unsigned int)h) << 16;
    return __builtin_bit_cast(float, u);
}

#define MFMA16(a, b, c) __builtin_amdgcn_mfma_f32_16x16x32_bf16((a), (b), (c), 0, 0, 0)

// Build split-bf16 A-fragments (hi+lo) from 8 consecutive fp32 values.
__device__ __forceinline__ void split_frag(const float* p, bf16x8& hi, bf16x8& lo) {
    f32x4 a = *(const f32x4*)p;
    f32x4 b = *(const f32x4*)(p + 4);
#pragma unroll
    for (int i = 0; i < 4; i++) {
        unsigned short h = f2bf_rne(a[i]);
        hi[i] = (short)h; lo[i] = (short)f2bf_rne(a[i] - bf2f(h));
        unsigned short h2 = f2bf_rne(b[i]);
        hi[4 + i] = (short)h2; lo[4 + i] = (short)f2bf_rne(b[i] - bf2f(h2));
    }
}
// Same, but non-temporal loads (pure read-once streams: x, zq).
__device__ __forceinline__ void split_frag_nt(const float* p, bf16x8& hi, bf16x8& lo) {
    f32x4 a = NTL((const f32x4*)p);
    f32x4 b = NTL((const f32x4*)(p + 4));
#pragma unroll
    for (int i = 0; i < 4; i++) {
        unsigned short h = f2bf_rne(a[i]);
        hi[i] = (short)h; lo[i] = (short)f2bf_rne(a[i] - bf2f(h));
        unsigned short h2 = f2bf_rne(b[i]);
        hi[4 + i] = (short)h2; lo[4 + i] = (short)f2bf_rne(b[i] - bf2f(h2));
    }
}

// Fragment-major packed offset for a B-matrix element (n, k), KB = K/32.
__device__ __forceinline__ size_t wpack_off(int n, int k, int KB) {
    int n16 = n >> 4, l15 = n & 15;
    int kb = k >> 5, lhi = (k >> 3) & 3, j = k & 7;
    return (((size_t)(n16 * KB + kb) * 4 + lhi) * 16 + l15) * 8 + j;
}

// Same layout for the LDS-resident h state (m over 32 batches, n over 512).
__device__ __forceinline__ int hfrag_off(int m, int n) {
    int m16 = m >> 4, l15m = m & 15;
    int kb = n >> 5, lhi = (n >> 3) & 3, j = n & 7;
    return (((m16 * 16 + kb) * 4 + lhi) * 16 + l15m) * 8 + j;
}

// ---------------------------------------------------------------------------
// Pack fp32 matrix into frag-major bf16 hi/lo (optional 2nd dest).
// kshift: 9 (K=512) or 8 (K=256).
// ---------------------------------------------------------------------------
__global__ void k_pack(const float* __restrict__ in, unsigned short* __restrict__ hi,
                       unsigned short* __restrict__ lo, unsigned short* __restrict__ hi2,
                       unsigned short* __restrict__ lo2, int total, int kshift) {
    int i = blockIdx.x * 256 + threadIdx.x;
    if (i < total) {
        int n = i >> kshift;
        int k = i & ((1 << kshift) - 1);
        float v = in[i];
        unsigned short h = f2bf_rne(v);
        unsigned short l = f2bf_rne(v - bf2f(h));
        size_t o = wpack_off(n, k, 1 << (kshift - 5));
        hi[o] = h;
        lo[o] = l;
        if (hi2) { hi2[o] = h; lo2[o] = l; }
    }
}

// ---------------------------------------------------------------------------
// fp32 matmul body: Out = A * Bm (512x512 row-major), blockIdx.x/y tile.
// Fused epilogue: optional packed (frag-major bf16 hi/lo) dests d1, d2.
// ---------------------------------------------------------------------------
__device__ __forceinline__ void mul_body(const float* __restrict__ A,
                                         const float* __restrict__ Bm,
                                         float* __restrict__ Out,
                                         unsigned short* __restrict__ d1h,
                                         unsigned short* __restrict__ d1l,
                                         unsigned short* __restrict__ d2h,
                                         unsigned short* __restrict__ d2l,
                                         float (*As)[33], float (*Bs)[33]) {
    int tx = threadIdx.x & 15, ty = threadIdx.x >> 4;
    int j0 = blockIdx.x * 32, i0 = blockIdx.y * 32;
    float a00 = 0.f, a01 = 0.f, a10 = 0.f, a11 = 0.f;
    int r  = threadIdx.x >> 3;
    int c4 = (threadIdx.x & 7) * 4;
    for (int kb = 0; kb < H_ / 32; kb++) {
        f32x4 va = *(const f32x4*)(A + (size_t)(i0 + r) * H_ + kb * 32 + c4);
        f32x4 vb = *(const f32x4*)(Bm + (size_t)(kb * 32 + r) * H_ + j0 + c4);
        __syncthreads();
        As[r][c4 + 0] = va[0]; As[r][c4 + 1] = va[1]; As[r][c4 + 2] = va[2]; As[r][c4 + 3] = va[3];
        Bs[r][c4 + 0] = vb[0]; Bs[r][c4 + 1] = vb[1]; Bs[r][c4 + 2] = vb[2]; Bs[r][c4 + 3] = vb[3];
        __syncthreads();
#pragma unroll
        for (int k = 0; k < 32; k++) {
            float b0 = Bs[k][tx * 2], b1 = Bs[k][tx * 2 + 1];
            float a0 = As[ty * 2][k], a1 = As[ty * 2 + 1][k];
            a00 += a0 * b0; a01 += a0 * b1; a10 += a1 * b0; a11 += a1 * b1;
        }
    }
    float vals[4] = {a00, a01, a10, a11};
#pragma unroll
    for (int q = 0; q < 4; q++) {
        int n = i0 + ty * 2 + (q >> 1);
        int k = j0 + tx * 2 + (q & 1);
        Out[(size_t)n * H_ + k] = vals[q];
        unsigned short h = f2bf_rne(vals[q]);
        unsigned short l = f2bf_rne(vals[q] - bf2f(h));
        size_t o = wpack_off(n, k, 16);
        if (d1h) { d1h[o] = h; d1l[o] = l; }
        if (d2h) { d2h[o] = h; d2l[o] = l; }
    }
}

__global__ __launch_bounds__(256) void k_mul(const float* __restrict__ A,
                                             const float* __restrict__ Bm,
                                             float* __restrict__ Out,
                                             unsigned short* __restrict__ d1h,
                                             unsigned short* __restrict__ d1l,
                                             unsigned short* __restrict__ d2h,
                                             unsigned short* __restrict__ d2l) {
    __shared__ float As[32][33];
    __shared__ float Bs[32][33];
    mul_body(A, Bm, Out, d1h, d1l, d2h, d2l, As, Bs);
}

// Two independent products per launch: z=0: W^3 = W*W^2 -> M1 (pack Pp2);
// z=1: W^4 = W^2*W^2 -> M2 (pack Pp3). M base = ws.
__global__ __launch_bounds__(256) void k_mul_l2(const float* __restrict__ Whh,
                                                float* __restrict__ ws,
                                                unsigned short* __restrict__ Pp_hi,
                                                unsigned short* __restrict__ Pp_lo) {
    __shared__ float As[32][33];
    __shared__ float Bs[32][33];
    size_t HH = (size_t)H_ * H_;
    if (blockIdx.z == 0)
        mul_body(Whh, ws, ws + HH, Pp_hi + 2 * HH, Pp_lo + 2 * HH, nullptr, nullptr, As, Bs);
    else
        mul_body(ws, ws, ws + 2 * HH, Pp_hi + 3 * HH, Pp_lo + 3 * HH, nullptr, nullptr, As, Bs);
}

// Four independent products: z=0: W^5=W*W^4->M3(Pp4); z=1: W^6=W^2*W^4->M4(Pp5);
// z=2: W^7=W^3*W^4->M5(Pp6); z=3: W^8=W^4*W^4->M6(Pp7+Qp0).
__global__ __launch_bounds__(256) void k_mul_l3(const float* __restrict__ Whh,
                                                float* __restrict__ ws,
                                                unsigned short* __restrict__ Pp_hi,
                                                unsigned short* __restrict__ Pp_lo,
                                                unsigned short* __restrict__ Qp_hi,
                                                unsigned short* __restrict__ Qp_lo) {
    __shared__ float As[32][33];
    __shared__ float Bs[32][33];
    size_t HH = (size_t)H_ * H_;
    float* M0 = ws;           // W^2
    float* M1 = ws + HH;      // W^3
    float* M2 = ws + 2 * HH;  // W^4
    int z = blockIdx.z;
    if (z == 0)
        mul_body(Whh, M2, ws + 3 * HH, Pp_hi + 4 * HH, Pp_lo + 4 * HH, nullptr, nullptr, As, Bs);
    else if (z == 1)
        mul_body(M0, M2, ws + 4 * HH, Pp_hi + 5 * HH, Pp_lo + 5 * HH, nullptr, nullptr, As, Bs);
    else if (z == 2)
        mul_body(M1, M2, ws + 5 * HH, Pp_hi + 6 * HH, Pp_lo + 6 * HH, nullptr, nullptr, As, Bs);
    else
        mul_body(M2, M2, ws + 6 * HH, Pp_hi + 7 * HH, Pp_lo + 7 * HH, Qp_hi, Qp_lo, As, Bs);
}

// ---------------------------------------------------------------------------
// Seed the chunk-carry scan inputs: v[0]=h0, v[c]=l_end(c-1) from zb.
// ---------------------------------------------------------------------------
__global__ void k_seed(const float* __restrict__ h0, const float* __restrict__ zb,
                       float* __restrict__ Va) {
    int i = blockIdx.x * 256 + threadIdx.x;  // over C*B*H
    int c = i >> 14;             // B*H = 16384
    int bn = i & 16383;
    int b = bn >> 9, n = bn & 511;
    Va[i] = (c == 0) ? h0[bn] : zb[((size_t)b * T_ + (c * S_CH - 1)) * H_ + n];
}

// ---------------------------------------------------------------------------
// One Kogge-Stone scan level via split-bf16 MFMA:
// Vout[c] = Vin[c] + Vin[c-s] @ (W^(S*s))^T  (c >= s), else copy.
// grid C_CH, block 1024 (16 waves; wave w owns 32-col n-slice, nt 0..1).
// Final level also writes the result as packed A-fragments (Ap_hi/lo) so
// k_carry can consume bf16x8 frags directly (no on-the-fly split VALU).
// ---------------------------------------------------------------------------
__global__ __launch_bounds__(1024) void k_scan2(const float* __restrict__ Vin,
                                                const unsigned short* __restrict__ Qp_hi,
                                                const unsigned short* __restrict__ Qp_lo,
                                                float* __restrict__ Vout, int s,
                                                unsigned short* __restrict__ Ap_hi,
                                                unsigned short* __restrict__ Ap_lo) {
    __shared__ __attribute__((aligned(16))) unsigned short hA[16384];
    __shared__ __attribute__((aligned(16))) unsigned short lA[16384];
    int c = blockIdx.x;
    int w = threadIdx.x >> 6;
    int lane = threadIdx.x & 63;
    int l15 = lane & 15, lhi = lane >> 4;
    size_t abase = (size_t)c << 14;   // c * 16384 (A-frag base for this chunk)

    if (c < s) {  // pure copy (+ optional pack)
        size_t base = (size_t)c * B_ * H_;
        for (int i = threadIdx.x * 4; i < B_ * H_; i += 4096) {
            f32x4 v = *(const f32x4*)(Vin + base + i);
            *(f32x4*)(Vout + base + i) = v;
            if (Ap_hi) {
                int m = i >> 9, n = i & 511;
#pragma unroll
                for (int q = 0; q < 4; q++) {
                    unsigned short h = f2bf_rne(v[q]);
                    size_t o = abase + hfrag_off(m, n + q);
                    Ap_hi[o] = h;
                    Ap_lo[o] = f2bf_rne(v[q] - bf2f(h));
                }
            }
        }
        return;
    }

    // stage Vin[c-s] as split-bf16 frag-major in LDS
    size_t src = (size_t)(c - s) * B_ * H_;
    for (int i = threadIdx.x; i < 16384; i += 1024) {
        float v = Vin[src + i];               // i = m*512 + n, row-major
        int m = i >> 9, n = i & 511;
        unsigned short hi = f2bf_rne(v);
        int o = hfrag_off(m, n);
        hA[o] = hi;
        lA[o] = f2bf_rne(v - bf2f(hi));
    }
    __syncthreads();

    // issue the additive Vin[c] loads early (overlap with MFMA)
    size_t dst = (size_t)c * B_ * H_;
    float ad[2][2][4];
#pragma unroll
    for (int mt = 0; mt < 2; mt++)
#pragma unroll
        for (int nt = 0; nt < 2; nt++) {
            int n = w * 32 + nt * 16 + l15;
#pragma unroll
            for (int r = 0; r < 4; r++) {
                int m = mt * 16 + lhi * 4 + r;
                ad[mt][nt][r] = Vin[dst + (size_t)m * H_ + n];
            }
        }

    f32x4 acc[2][2];
#pragma unroll
    for (int mt = 0; mt < 2; mt++)
#pragma unroll
        for (int nt = 0; nt < 2; nt++) acc[mt][nt] = (f32x4){0.f, 0.f, 0.f, 0.f};

    for (int kb = 0; kb < 16; kb++) {
        bf16x8 ah0 = *(const bf16x8*)&hA[(kb << 9) + lane * 8];
        bf16x8 ah1 = *(const bf16x8*)&hA[((16 + kb) << 9) + lane * 8];
        bf16x8 al0 = *(const bf16x8*)&lA[(kb << 9) + lane * 8];
        bf16x8 al1 = *(const bf16x8*)&lA[((16 + kb) << 9) + lane * 8];
#pragma unroll
        for (int nt = 0; nt < 2; nt++) {
            size_t wb = (((size_t)(w * 2 + nt) * 16 + kb) << 9) + lane * 8;
            bf16x8 bh = *(const bf16x8*)(Qp_hi + wb);
            bf16x8 bl = *(const bf16x8*)(Qp_lo + wb);
            acc[0][nt] = MFMA16(ah0, bh, acc[0][nt]);
            acc[0][nt] = MFMA16(al0, bh, acc[0][nt]);
            acc[0][nt] = MFMA16(ah0, bl, acc[0][nt]);
            acc[1][nt] = MFMA16(ah1, bh, acc[1][nt]);
            acc[1][nt] = MFMA16(al1, bh, acc[1][nt]);
            acc[1][nt] = MFMA16(ah1, bl, acc[1][nt]);
        }
    }
#pragma unroll
    for (int mt = 0; mt < 2; mt++)
#pragma unroll
        for (int nt = 0; nt < 2; nt++) {
            int n = w * 32 + nt * 16 + l15;
#pragma unroll
            for (int r = 0; r < 4; r++) {
                int m = mt * 16 + lhi * 4 + r;
                float v = acc[mt][nt][r] + ad[mt][nt][r];
                Vout[dst + (size_t)m * H_ + n] = v;
                if (Ap_hi) {
                    unsigned short h = f2bf_rne(v);
                    size_t o = abase + hfrag_off(m, n);
                    Ap_hi[o] = h;
                    Ap_lo[o] = f2bf_rne(v - bf2f(h));
                }
            }
        }
}

// ---------------------------------------------------------------------------
// K0: zb[b][t][h] = x[b][t][:] @ W_ih^T + (b_ih + b_hh), fp32, into the z
// region of d_out. x split hi/lo on the fly; W_ih pre-split+packed; 3 MFMAs.
// grid (T/64, B), block 512 (8 waves; wave w owns n-slice 64w..64w+63)
// ---------------------------------------------------------------------------
__global__ __launch_bounds__(512) void k_xw(const float* __restrict__ x,
                                            const unsigned short* __restrict__ Wp_hi,
                                            const unsigned short* __restrict__ Wp_lo,
                                            const float* __restrict__ bih,
                                            const float* __restrict__ bhh,
                                            float* __restrict__ zb) {
    int b  = blockIdx.y;
    int t0 = blockIdx.x * 64;
    int w    = threadIdx.x >> 6;
    int lane = threadIdx.x & 63;
    int l15 = lane & 15, lhi = lane >> 4;
    int nb = w * 64;

    f32x4 acc[4][4];  // [mt][nt]
    for (int mt = 0; mt < 4; mt++)
        for (int nt = 0; nt < 4; nt++)
            acc[mt][nt] = (f32x4){0.f, 0.f, 0.f, 0.f};

    const float* xb = x + (size_t)b * T_ * D_;
    for (int kb = 0; kb < D_ / 32; kb++) {
        int kofs = kb * 32 + lhi * 8;
        bf16x8 ah[4], al[4];
#pragma unroll
        for (int mt = 0; mt < 4; mt++) {
            int t = t0 + mt * 16 + l15;
            split_frag_nt(xb + (size_t)t * D_ + kofs, ah[mt], al[mt]);
        }
#pragma unroll
        for (int nt = 0; nt < 4; nt++) {
            size_t wb = (((size_t)(w * 4 + nt) * 8 + kb) << 9) + lane * 8;  // KB=8
            bf16x8 bh = *(const bf16x8*)(Wp_hi + wb);
            bf16x8 bl = *(const bf16x8*)(Wp_lo + wb);
#pragma unroll
            for (int mt = 0; mt < 4; mt++) {
                acc[mt][nt] = MFMA16(ah[mt], bh, acc[mt][nt]);
                acc[mt][nt] = MFMA16(al[mt], bh, acc[mt][nt]);
                acc[mt][nt] = MFMA16(ah[mt], bl, acc[mt][nt]);
            }
        }
    }
#pragma unroll
    for (int nt = 0; nt < 4; nt++) {
        int n = nb + nt * 16 + l15;
        float bias = bih[n] + bhh[n];
#pragma unroll
        for (int mt = 0; mt < 4; mt++) {
#pragma unroll
            for (int r = 0; r < 4; r++) {
                int t = t0 + mt * 16 + lhi * 4 + r;
                zb[((size_t)b * T_ + t) * H_ + n] = acc[mt][nt][r] + bias;
            }
        }
    }
}

// ---------------------------------------------------------------------------
// Phase 1: per-chunk local recurrence l_t = xw_t + l_{t-1} @ W_hh^T (from 0),
// in place over zb (fp32, [b][t][h]). State fp32 via split-bf16 hi/lo LDS.
// grid C_CH, block 1024 (16 waves; wave w owns 32-col n-slice, nt 0..1).
// Weights streamed from L2 each step (register preload spills at 1024 thr).
// ---------------------------------------------------------------------------
__global__ __launch_bounds__(1024) void k_phase1(const unsigned short* __restrict__ Wp_hi,
                                                 const unsigned short* __restrict__ Wp_lo,
                                                 float* __restrict__ zb) {
    __shared__ __attribute__((aligned(16))) unsigned short hA[16384];
    __shared__ __attribute__((aligned(16))) unsigned short lA[16384];
    int c = blockIdx.x;
    int w = threadIdx.x >> 6;
    int lane = threadIdx.x & 63;
    int l15 = lane & 15, lhi = lane >> 4;
    // no LDS init needed: j==0 skips the MFMA pass entirely

    for (int j = 0; j < S_CH; j++) {
        int t = c * S_CH + j;
        // issue this step's xw loads early; they resolve under the MFMA loop
        float xw[2][2][4];
#pragma unroll
        for (int mt = 0; mt < 2; mt++)
#pragma unroll
            for (int nt = 0; nt < 2; nt++) {
                int n = w * 32 + nt * 16 + l15;
#pragma unroll
                for (int r = 0; r < 4; r++) {
                    int b = mt * 16 + lhi * 4 + r;
                    xw[mt][nt][r] = zb[((size_t)b * T_ + t) * H_ + n];
                }
            }
        f32x4 acc[2][2];
#pragma unroll
        for (int mt = 0; mt < 2; mt++)
#pragma unroll
            for (int nt = 0; nt < 2; nt++) acc[mt][nt] = (f32x4){0.f, 0.f, 0.f, 0.f};
        if (j > 0) {
            for (int kb = 0; kb < 16; kb++) {
                bf16x8 ah0 = *(const bf16x8*)&hA[(kb << 9) + lane * 8];
                bf16x8 ah1 = *(const bf16x8*)&hA[((16 + kb) << 9) + lane * 8];
                bf16x8 al0 = *(const bf16x8*)&lA[(kb << 9) + lane * 8];
                bf16x8 al1 = *(const bf16x8*)&lA[((16 + kb) << 9) + lane * 8];
#pragma unroll
                for (int nt = 0; nt < 2; nt++) {
                    size_t wb = (((size_t)(w * 2 + nt) * 16 + kb) << 9) + lane * 8;
                    bf16x8 bh = *(const bf16x8*)(Wp_hi + wb);
                    bf16x8 bl = *(const bf16x8*)(Wp_lo + wb);
                    acc[0][nt] = MFMA16(ah0, bh, acc[0][nt]);
                    acc[0][nt] = MFMA16(al0, bh, acc[0][nt]);
                    acc[0][nt] = MFMA16(ah0, bl, acc[0][nt]);
                    acc[1][nt] = MFMA16(ah1, bh, acc[1][nt]);
                    acc[1][nt] = MFMA16(al1, bh, acc[1][nt]);
                    acc[1][nt] = MFMA16(ah1, bl, acc[1][nt]);
                }
            }
        }
        __syncthreads();  // all waves done reading previous h before overwrite
#pragma unroll
        for (int mt = 0; mt < 2; mt++) {
#pragma unroll
            for (int nt = 0; nt < 2; nt++) {
                int n = w * 32 + nt * 16 + l15;
#pragma unroll
                for (int r = 0; r < 4; r++) {
                    int b = mt * 16 + lhi * 4 + r;
                    float v = acc[mt][nt][r] + xw[mt][nt][r];
                    zb[((size_t)b * T_ + t) * H_ + n] = v;  // l_t (fp32)
                    unsigned short hi = f2bf_rne(v);
                    int o = hfrag_off(b, n);
                    hA[o] = hi;
                    lA[o] = f2bf_rne(v - bf2f(hi));
                }
            }
        }
        __syncthreads();
    }
}

// ---------------------------------------------------------------------------
// Carry broadcast as ONE GEMM (replaces the serial phase 3):
//   zb[b][c*8+j][n] += Hin[c][b][:] @ (W^(j+1))^T
// A = Ap (8192 x 512 PRE-PACKED split-bf16 frags, from scan2's final level),
// B = Pp (stacked W^1..W^8, 4096 x 512 packed). M=8192, N=4096, K=512.
// BM=128, BN=256, block 512 (8 waves as 2M x 4N). No split VALU in the loop.
// XCD swizzle: each XCD owns 8 contiguous M-tiles (A L2-resident) x 16 panels.
// ---------------------------------------------------------------------------
__global__ __launch_bounds__(512) void k_carry(const unsigned short* __restrict__ Ap_hi,
                                               const unsigned short* __restrict__ Ap_lo,
                                               const unsigned short* __restrict__ Pp_hi,
                                               const unsigned short* __restrict__ Pp_lo,
                                               float* __restrict__ zb) {
    int bid = blockIdx.x;
    int xcd = bid & 7;
    int idx = bid >> 3;                       // 0..127
    int mtile  = xcd * 8 + (idx & 7);         // 0..63 (8 contiguous per XCD)
    int npanel = idx >> 3;                    // 0..15
    int w = threadIdx.x >> 6, lane = threadIdx.x & 63;
    int l15 = lane & 15, lhi = lane >> 4;
    int wm = w >> 2, wn = w & 3;
    int m0 = mtile * 128 + wm * 64;
    int m16b = m0 >> 4;                       // base 16-row fragment index
    int n16base = npanel * 16 + wn * 4;       // global 16-col fragment index

    f32x4 acc[4][4];
#pragma unroll
    for (int mt = 0; mt < 4; mt++)
#pragma unroll
        for (int nt = 0; nt < 4; nt++) acc[mt][nt] = (f32x4){0.f, 0.f, 0.f, 0.f};

    for (int kb = 0; kb < 16; kb++) {
        bf16x8 ah[4], al[4];
#pragma unroll
        for (int mt = 0; mt < 4; mt++) {
            size_t ao = (((size_t)(m16b + mt) * 16 + kb) << 9) + lane * 8;
            ah[mt] = *(const bf16x8*)(Ap_hi + ao);
            al[mt] = *(const bf16x8*)(Ap_lo + ao);
        }
#pragma unroll
        for (int nt = 0; nt < 4; nt++) {
            size_t wb = (((size_t)(n16base + nt) * 16 + kb) << 9) + lane * 8;
            bf16x8 bh = *(const bf16x8*)(Pp_hi + wb);
            bf16x8 bl = *(const bf16x8*)(Pp_lo + wb);
#pragma unroll
            for (int mt = 0; mt < 4; mt++) {
                acc[mt][nt] = MFMA16(ah[mt], bh, acc[mt][nt]);
                acc[mt][nt] = MFMA16(al[mt], bh, acc[mt][nt]);
                acc[mt][nt] = MFMA16(ah[mt], bl, acc[mt][nt]);
            }
        }
    }
    // epilogue: z_t = l_t + acc, scattered into zb[b][t][n]
#pragma unroll
    for (int nt = 0; nt < 4; nt++) {
        int col = (n16base + nt) * 16 + l15;  // 0..4095
        int j = col >> 9, n = col & 511;
#pragma unroll
        for (int mt = 0; mt < 4; mt++) {
#pragma unroll
            for (int r = 0; r < 4; r++) {
                int m = m0 + mt * 16 + lhi * 4 + r;   // (c,b) row
                int c = m >> 5, b = m & 31;
                size_t zi = ((size_t)b * T_ + (c * S_CH + j)) * H_ + n;
                zb[zi] += acc[mt][nt][r];
            }
        }
    }
}

// ---------------------------------------------------------------------------
// K5: logits = z @ W_lin^T + b_lin, fused softmax over O=256, fp32 out.
// grid (B*T/64), block 256 (4 waves; wave w owns rows 16w..16w+15, all cols).
// ---------------------------------------------------------------------------
__global__ __launch_bounds__(256) void k_logits(const float* __restrict__ zq,
                                                const unsigned short* __restrict__ Wp_hi,
                                                const float* __restrict__ blin,
                                                float* __restrict__ out) {
    size_t row0 = (size_t)blockIdx.x * 64;
    int w = threadIdx.x >> 6, lane = threadIdx.x & 63;
    int l15 = lane & 15, lhi = lane >> 4;

    f32x4 acc[16];
#pragma unroll
    for (int nt = 0; nt < 16; nt++) acc[nt] = (f32x4){0.f, 0.f, 0.f, 0.f};

    const float* arow = zq + (row0 + (size_t)w * 16 + l15) * H_;
    for (int kb = 0; kb < 16; kb++) {
        int kofs = kb * 32 + lhi * 8;
        bf16x8 ah, al;
        split_frag_nt(arow + kofs, ah, al);
#pragma unroll
        for (int nt = 0; nt < 16; nt++) {
            size_t wb = (((size_t)nt * 16 + kb) << 9) + lane * 8;  // n16 = nt, KB=16
            bf16x8 bh = *(const bf16x8*)(Wp_hi + wb);
            acc[nt] = MFMA16(ah, bh, acc[nt]);
            acc[nt] = MFMA16(al, bh, acc[nt]);
        }
    }
#pragma unroll
    for (int nt = 0; nt < 16; nt++) {
        float bb = blin[nt * 16 + l15];
#pragma unroll
        for (int r = 0; r < 4; r++) acc[nt][r] += bb;
    }
    float rmax[4], rinv[4];
#pragma unroll
    for (int r = 0; r < 4; r++) {
        float mx = -INFINITY;
#pragma unroll
        for (int nt = 0; nt < 16; nt++) mx = fmaxf(mx, acc[nt][r]);
        for (int s = 1; s < 16; s <<= 1) mx = fmaxf(mx, __shfl_xor(mx, s));
        float sum = 0.f;
#pragma unroll
        for (int nt = 0; nt < 16; nt++) sum += __expf(acc[nt][r] - mx);
        for (int s = 1; s < 16; s <<= 1) sum += __shfl_xor(sum, s);
        rmax[r] = mx;
        rinv[r] = 1.f / sum;
    }
#pragma unroll
    for (int nt = 0; nt < 16; nt++) {
#pragma unroll
        for (int r = 0; r < 4; r++) {
            float e = __expf(acc[nt][r] - rmax[r]) * rinv[r];
            size_t row = row0 + (size_t)w * 16 + lhi * 4 + r;
            out[row * O_ + nt * 16 + l15] = e;
        }
    }
}

// ---------------------------------------------------------------------------
extern "C" void kernel_launch(void* const* d_in, const int* in_sizes, int n_in,
                              void* d_out, int out_size, void* d_ws, size_t ws_size,
                              hipStream_t stream) {
    const float* x    = (const float*)d_in[0];
    const float* h0   = (const float*)d_in[1];
    const float* Wih  = (const float*)d_in[2];
    const float* Whh  = (const float*)d_in[3];
    const float* bih  = (const float*)d_in[4];
    const float* bhh  = (const float*)d_in[5];
    const float* Wlin = (const float*)d_in[6];
    const float* blin = (const float*)d_in[7];

    float* out  = (float*)d_out;
    float* zout = out + (size_t)B_ * T_ * O_;  // z region of d_out (fp32, in-place)

    // ws layout (~15 MB): M[0..13] fp32 power matrices | small packed weights.
    // Softmax-out region of d_out (64 MB, dead until k_logits) hosts:
    // Va [0,16) | Vb [16,32) | Pp [32,40) | Qp [40,48) | Ap [48,64).
    float* ws = (float*)d_ws;
    size_t HH = (size_t)H_ * H_;
    unsigned short* Wih_hi  = (unsigned short*)(ws + (size_t)14 * HH);
    unsigned short* Wih_lo  = Wih_hi + (size_t)H_ * D_;
    unsigned short* Wlin_hi = Wih_lo + (size_t)H_ * D_;
    unsigned short* Wlin_lo = Wlin_hi + (size_t)O_ * H_;

    float* Va = out;                            // [0,16MB)
    float* Vb = out + (size_t)C_CH * B_ * H_;   // [16,32MB)
    unsigned short* Pp_hi = (unsigned short*)((char*)d_out + (size_t)32 * 1024 * 1024);
    unsigned short* Pp_lo = Pp_hi + (size_t)8 * HH;   // [36,40MB)
    unsigned short* Qp_hi = Pp_lo + (size_t)8 * HH;   // [40,44MB)
    unsigned short* Qp_lo = Qp_hi + (size_t)8 * HH;   // [44,48MB)
    unsigned short* Ap_hi = Qp_lo + (size_t)8 * HH;   // [48,56MB)
    unsigned short* Ap_lo = Ap_hi + (size_t)C_CH * B_ * H_;  // [56,64MB) < 64MB ✓

    unsigned short* nul = nullptr;

    // Pack direct-use weights. Whh packed once into Pp slice 0 (phase1 reads
    // the same layout there).
    k_pack<<<dim3((H_ * H_) / 256), 256, 0, stream>>>(Whh, Pp_hi, Pp_lo, nul, nul, H_ * H_, 9);
    k_pack<<<dim3((H_ * D_) / 256), 256, 0, stream>>>(Wih, Wih_hi, Wih_lo, nul, nul, H_ * D_, 8);
    k_pack<<<dim3((O_ * H_) / 256), 256, 0, stream>>>(Wlin, Wlin_hi, Wlin_lo, nul, nul, O_ * H_, 9);

    // fp32 power chain with fused packing, merged independent products:
    // W^2 -> M0 (Pp1); {W^3,W^4} -> M1,M2 (Pp2,Pp3); {W^5..W^8} -> M3..M6
    // (Pp4..Pp7, Qp0); then 7 serial squarings W^16..W^1024 -> Qp1..Qp7.
    dim3 g16(16, 16);
#define QPH(s) (Qp_hi + (size_t)(s) * HH)
#define QPL(s) (Qp_lo + (size_t)(s) * HH)
    k_mul<<<g16, 256, 0, stream>>>(Whh, Whh, ws, Pp_hi + HH, Pp_lo + HH, nul, nul); // W^2
    k_mul_l2<<<dim3(16, 16, 2), 256, 0, stream>>>(Whh, ws, Pp_hi, Pp_lo);           // W^3,W^4
    k_mul_l3<<<dim3(16, 16, 4), 256, 0, stream>>>(Whh, ws, Pp_hi, Pp_lo, Qp_hi, Qp_lo); // W^5..W^8
    for (int i = 7; i < 14; i++)                      // W^16..W^1024 -> Qp 1..7
        k_mul<<<g16, 256, 0, stream>>>(ws + (size_t)(i - 1) * HH, ws + (size_t)(i - 1) * HH,
                                       ws + (size_t)i * HH, QPH(i - 6), QPL(i - 6), nul, nul);
#undef QPH
#undef QPL

    // xw into z region
    k_xw<<<dim3(T_ / 64, B_), 512, 0, stream>>>(x, Wih_hi, Wih_lo, bih, bhh, zout);

    // local chunk scans (256 chunks of 8 steps), 16 waves/block
    k_phase1<<<dim3(C_CH), 1024, 0, stream>>>(Pp_hi, Pp_lo, zout);

    // chunk-carry Kogge-Stone scan (split-bf16 MFMA): level l shift 2^l.
    // Final level (l=7) also emits packed A-frags for k_carry.
    k_seed<<<dim3((C_CH * B_ * H_) / 256), 256, 0, stream>>>(h0, zout, Va);
    {
        float* vin = Va;
        float* vout = Vb;
        int s = 1;
        for (int l = 0; l < 8; l++) {
            unsigned short* ah = (l == 7) ? Ap_hi : nul;
            unsigned short* al = (l == 7) ? Ap_lo : nul;
            k_scan2<<<dim3(C_CH), 1024, 0, stream>>>(
                vin, Qp_hi + (size_t)l * HH, Qp_lo + (size_t)l * HH, vout, s, ah, al);
            float* tmp = vin; vin = vout; vout = tmp;
            s <<= 1;
        }
        // 8 swaps -> final result back in Va (+ packed in Ap)
    }

    // carry broadcast as one big GEMM + in-place add into zb
    k_carry<<<dim3(1024), 512, 0, stream>>>(Ap_hi, Ap_lo, Pp_hi, Pp_lo, zout);

    // logits + softmax
    k_logits<<<dim3((B_ * T_) / 64), 256, 0, stream>>>(zout, Wlin_hi, blin, out);
}